// Round 1
// baseline (771.020 us; speedup 1.0000x reference)
//
#include <hip/hip_runtime.h>
#include <hip/hip_bf16.h>
#include <cstdint>

#define DD 128

// W[r] = sum_b comp[r,b] * basis[b]  -> [R][128][128]
__global__ __launch_bounds__(256) void wcomb_kernel(
    const float* __restrict__ basis, const float* __restrict__ comp,
    float* __restrict__ W)
{
    int idx = blockIdx.x * 256 + threadIdx.x;   // 0 .. 8*16384
    int r = idx >> 14;
    int io = idx & 16383;
    float acc = 0.f;
    #pragma unroll
    for (int b = 0; b < 4; ++b)
        acc += comp[r * 4 + b] * basis[b * 16384 + io];
    W[idx] = acc;
}

// per-edge: S[etype][dst] += h[src]; deg[dst] += 1
__global__ __launch_bounds__(256) void scatter_kernel(
    const float* __restrict__ h, const int* __restrict__ src,
    const int* __restrict__ dst, const int* __restrict__ eid,
    const int* __restrict__ etype_all, float* __restrict__ S,
    float* __restrict__ deg, int nE, int ndst)
{
    int e = blockIdx.x * 2 + (threadIdx.x >> 7);
    if (e >= nE) return;
    int f = threadIdx.x & 127;
    int s = src[e];
    int d = dst[e];
    int r = etype_all[eid[e]];
    float v = h[(size_t)s * DD + f];
    atomicAdd(&S[((size_t)r * ndst + d) * DD + f], v);
    if (f == 0) atomicAdd(&deg[d], 1.0f);
}

// one BK=32 sweep of C[64x128] += A[64x128-tile] @ W[128x128]
__device__ __forceinline__ void mm_tile(
    const float* __restrict__ A, const float* __restrict__ W,
    float acc[8][4], float* As, float* Bs,
    int row0, int nrows, int tid, int cg, int rg)
{
    for (int k0 = 0; k0 < 128; k0 += 32) {
        __syncthreads();
        {
            // load A tile transposed: As[k][m], stride 68 (16B-aligned pad)
            int r  = tid >> 3;          // 0..31
            int kk = (tid & 7) << 2;    // 0,4,..,28
            #pragma unroll
            for (int half = 0; half < 2; ++half) {
                int m = r + 32 * half;
                int row = row0 + m;
                float4 v = make_float4(0.f, 0.f, 0.f, 0.f);
                if (row < nrows)
                    v = *(const float4*)&A[(size_t)row * DD + k0 + kk];
                As[(kk + 0) * 68 + m] = v.x;
                As[(kk + 1) * 68 + m] = v.y;
                As[(kk + 2) * 68 + m] = v.z;
                As[(kk + 3) * 68 + m] = v.w;
            }
        }
        {
            // load B tile 32x128, natural layout
            const float4* Wv = (const float4*)(W + (size_t)k0 * DD);
            float4* Bv = (float4*)Bs;
            #pragma unroll
            for (int j = 0; j < 4; ++j)
                Bv[tid + 256 * j] = Wv[tid + 256 * j];
        }
        __syncthreads();
        #pragma unroll
        for (int kk = 0; kk < 32; ++kk) {
            float4 b4 = *(const float4*)&Bs[kk * DD + (cg << 2)];
            float4 a0 = *(const float4*)&As[kk * 68 + (rg << 3)];
            float4 a1 = *(const float4*)&As[kk * 68 + (rg << 3) + 4];
            float a[8] = {a0.x, a0.y, a0.z, a0.w, a1.x, a1.y, a1.z, a1.w};
            float b[4] = {b4.x, b4.y, b4.z, b4.w};
            #pragma unroll
            for (int i = 0; i < 8; ++i)
                #pragma unroll
                for (int j = 0; j < 4; ++j)
                    acc[i][j] = fmaf(a[i], b[j], acc[i][j]);
        }
    }
}

// C = (sum_p Ap[p] @ Wp[p]) * 1/max(deg,1)  + Ar @ Wr + bias   [+relu]
__global__ __launch_bounds__(256) void gemm_planes_kernel(
    const float* __restrict__ Ap, const float* __restrict__ Wp, int nplanes,
    const float* __restrict__ Ar, const float* __restrict__ Wr,
    const float* __restrict__ bias, const float* __restrict__ deg,
    float* __restrict__ C, int nrows, int do_relu)
{
    __shared__ float As[32 * 68];
    __shared__ float Bs[32 * DD];
    int tid = threadIdx.x;
    int row0 = blockIdx.x * 64;
    int cg = tid & 31;      // col group: cols 4*cg..4*cg+3
    int rg = tid >> 5;      // row group: rows 8*rg..8*rg+7
    float acc[8][4];
    #pragma unroll
    for (int i = 0; i < 8; ++i)
        #pragma unroll
        for (int j = 0; j < 4; ++j) acc[i][j] = 0.f;

    for (int p = 0; p < nplanes; ++p) {
        const float* A = Ap + (size_t)p * nrows * DD;
        const float* W = Wp + (size_t)p * DD * DD;
        mm_tile(A, W, acc, As, Bs, row0, nrows, tid, cg, rg);
    }
    if (deg != nullptr) {
        #pragma unroll
        for (int i = 0; i < 8; ++i) {
            int row = row0 + (rg << 3) + i;
            float s = 1.f;
            if (row < nrows) s = 1.f / fmaxf(deg[row], 1.f);
            #pragma unroll
            for (int j = 0; j < 4; ++j) acc[i][j] *= s;
        }
    }
    if (Ar != nullptr)
        mm_tile(Ar, Wr, acc, As, Bs, row0, nrows, tid, cg, rg);

    float4 bb = *(const float4*)&bias[cg << 2];
    #pragma unroll
    for (int i = 0; i < 8; ++i) {
        int row = row0 + (rg << 3) + i;
        if (row < nrows) {
            float4 v;
            v.x = acc[i][0] + bb.x;
            v.y = acc[i][1] + bb.y;
            v.z = acc[i][2] + bb.z;
            v.w = acc[i][3] + bb.w;
            if (do_relu) {
                v.x = fmaxf(v.x, 0.f); v.y = fmaxf(v.y, 0.f);
                v.z = fmaxf(v.z, 0.f); v.w = fmaxf(v.w, 0.f);
            }
            *(float4*)&C[(size_t)row * DD + (cg << 2)] = v;
        }
    }
}

// y = relu(layernorm(x)*g+b), one wave per row
__global__ __launch_bounds__(256) void ln_relu_kernel(
    const float* __restrict__ x, const float* __restrict__ g,
    const float* __restrict__ b, float* __restrict__ y, int nrows)
{
    int row = blockIdx.x * 4 + (threadIdx.x >> 6);
    if (row >= nrows) return;
    int lane = threadIdx.x & 63;
    float v0 = x[(size_t)row * DD + lane];
    float v1 = x[(size_t)row * DD + lane + 64];
    float s = v0 + v1;
    #pragma unroll
    for (int o = 32; o > 0; o >>= 1) s += __shfl_down(s, o);
    s = __shfl(s, 0);
    float mu = s * (1.f / 128.f);
    float d0 = v0 - mu, d1 = v1 - mu;
    float q = d0 * d0 + d1 * d1;
    #pragma unroll
    for (int o = 32; o > 0; o >>= 1) q += __shfl_down(q, o);
    q = __shfl(q, 0);
    float rstd = rsqrtf(q * (1.f / 128.f) + 1e-5f);
    float y0 = d0 * rstd * g[lane] + b[lane];
    float y1 = d1 * rstd * g[lane + 64] + b[lane + 64];
    y[(size_t)row * DD + lane]      = fmaxf(y0, 0.f);
    y[(size_t)row * DD + lane + 64] = fmaxf(y1, 0.f);
}

extern "C" void kernel_launch(void* const* d_in, const int* in_sizes, int n_in,
                              void* d_out, int out_size, void* d_ws, size_t ws_size,
                              hipStream_t stream)
{
    const float* x     = (const float*)d_in[0];
    const int* src0    = (const int*)d_in[1];
    const int* dst0    = (const int*)d_in[2];
    const int* eid0    = (const int*)d_in[3];
    const int* src1    = (const int*)d_in[4];
    const int* dst1    = (const int*)d_in[5];
    const int* eid1    = (const int*)d_in[6];
    const int* etype   = (const int*)d_in[7];
    const float* preW  = (const float*)d_in[8];
    const float* preb  = (const float*)d_in[9];
    const float* basis0 = (const float*)d_in[10];
    const float* comp0  = (const float*)d_in[11];
    const float* root0  = (const float*)d_in[12];
    const float* bias0  = (const float*)d_in[13];
    const float* g0    = (const float*)d_in[14];
    const float* be0   = (const float*)d_in[15];
    const float* basis1 = (const float*)d_in[16];
    const float* comp1  = (const float*)d_in[17];
    const float* root1  = (const float*)d_in[18];
    const float* bias1  = (const float*)d_in[19];
    const float* g1    = (const float*)d_in[20];
    const float* be1   = (const float*)d_in[21];
    const float* postW = (const float*)d_in[22];
    const float* postb = (const float*)d_in[23];
    float* out = (float*)d_out;

    const int N0 = 120000, N1 = 30000, N2 = 6000;
    const int E0 = 480000, E1 = 96000;

    float* ws = (float*)d_ws;
    size_t o = 0;
    float* h0 = ws + o; o += (size_t)N0 * DD;        // 15,360,000 f
    float* S0 = ws + o; o += (size_t)8 * N1 * DD;    // 30,720,000 f
    float* c0 = ws + o; o += (size_t)N1 * DD;        //  3,840,000 f
    float* h1 = ws + o; o += (size_t)N1 * DD;        //  3,840,000 f
    float* S1 = ws + o; o += (size_t)8 * N2 * DD;    //  6,144,000 f
    float* c1 = ws + o; o += (size_t)N2 * DD;        //    768,000 f
    float* h2 = ws + o; o += (size_t)N2 * DD;        //    768,000 f
    float* deg0 = ws + o; o += N1;
    float* deg1 = ws + o; o += N2;                   // deg0..deg1 contiguous
    float* W0 = ws + o; o += 8 * DD * DD;
    float* W1 = ws + o; o += 8 * DD * DD;
    // total ~61.8M floats ~= 247 MB

    hipMemsetAsync(S0, 0, (size_t)8 * N1 * DD * sizeof(float), stream);
    hipMemsetAsync(S1, 0, (size_t)8 * N2 * DD * sizeof(float), stream);
    hipMemsetAsync(deg0, 0, (size_t)(N1 + N2) * sizeof(float), stream);

    wcomb_kernel<<<512, 256, 0, stream>>>(basis0, comp0, W0);
    wcomb_kernel<<<512, 256, 0, stream>>>(basis1, comp1, W1);

    // h0 = relu(x @ preW + preb)
    gemm_planes_kernel<<<(N0 + 63) / 64, 256, 0, stream>>>(
        nullptr, nullptr, 0, x, preW, preb, nullptr, h0, N0, 1);

    // layer 0: scatter + conv + ln/relu
    scatter_kernel<<<(E0 + 1) / 2, 256, 0, stream>>>(
        h0, src0, dst0, eid0, etype, S0, deg0, E0, N1);
    gemm_planes_kernel<<<(N1 + 63) / 64, 256, 0, stream>>>(
        S0, W0, 8, h0, root0, bias0, deg0, c0, N1, 0);
    ln_relu_kernel<<<(N1 + 3) / 4, 256, 0, stream>>>(c0, g0, be0, h1, N1);

    // layer 1
    scatter_kernel<<<(E1 + 1) / 2, 256, 0, stream>>>(
        h1, src1, dst1, eid1, etype, S1, deg1, E1, N2);
    gemm_planes_kernel<<<(N2 + 63) / 64, 256, 0, stream>>>(
        S1, W1, 8, h1, root1, bias1, deg1, c1, N2, 0);
    ln_relu_kernel<<<(N2 + 3) / 4, 256, 0, stream>>>(c1, g1, be1, h2, N2);

    // out = h2 @ postW + postb
    gemm_planes_kernel<<<(N2 + 63) / 64, 256, 0, stream>>>(
        nullptr, nullptr, 0, h2, postW, postb, nullptr, out, N2, 0);
}

// Round 2
// 464.645 us; speedup vs baseline: 1.6594x; 1.6594x over previous
//
#include <hip/hip_runtime.h>
#include <cstdint>

#define DD 128

typedef unsigned short u16;
typedef __attribute__((ext_vector_type(8))) short bf16x8;
typedef __attribute__((ext_vector_type(4))) float f32x4;

__device__ __forceinline__ u16 f2b(float f) {
    union { float f; unsigned u; } a; a.f = f;
    unsigned r = (a.u + 0x7fffu + ((a.u >> 16) & 1u)) >> 16;
    return (u16)r;
}
__device__ __forceinline__ float b2f(u16 u) {
    union { unsigned u; float f; } a; a.u = ((unsigned)u) << 16;
    return a.f;
}

// ---- weight convert: 12 matrices [k][n] f32 -> Wt [n][k] bf16 ----
struct WtJob { const float* src[12]; };
__global__ __launch_bounds__(256) void wconv_kernel(WtJob job, u16* __restrict__ dst)
{
    int g = blockIdx.x * 256 + threadIdx.x;      // 0 .. 12*16384
    int m = g >> 14;
    int e = g & 16383;
    int n = e >> 7, k = e & 127;
    dst[g] = f2b(job.src[m][k * DD + n]);
}

// ---- CSR build ----
__global__ __launch_bounds__(256) void hist_kernel(
    const int* __restrict__ dst, int* __restrict__ cnt, int nE)
{
    int e = blockIdx.x * 256 + threadIdx.x;
    if (e < nE) atomicAdd(&cnt[dst[e]], 1);
}

__global__ __launch_bounds__(1024) void scan_kernel(
    const int* __restrict__ cnt, int* __restrict__ off, int n)
{
    __shared__ int wsum[16];
    __shared__ int carry_s;
    int tid = threadIdx.x, lane = tid & 63, w = tid >> 6;
    if (tid == 0) carry_s = 0;
    __syncthreads();
    for (int base = 0; base < n; base += 1024) {
        int i = base + tid;
        int v = (i < n) ? cnt[i] : 0;
        int s = v;
        #pragma unroll
        for (int o = 1; o < 64; o <<= 1) {
            int t = __shfl_up(s, o);
            if (lane >= o) s += t;
        }
        if (lane == 63) wsum[w] = s;
        __syncthreads();
        int carry = carry_s;
        int woff = 0;
        for (int j = 0; j < w; ++j) woff += wsum[j];
        if (i < n) off[i] = carry + woff + s - v;
        __syncthreads();
        if (tid == 1023) carry_s = carry + woff + s;
        __syncthreads();
    }
    if (threadIdx.x == 0) off[n] = carry_s;
}

__global__ __launch_bounds__(256) void fill_kernel(
    const int* __restrict__ src, const int* __restrict__ dst,
    const int* __restrict__ eid, const int* __restrict__ etype,
    const int* __restrict__ off, int* __restrict__ cur,
    int* __restrict__ epack, int nE)
{
    int e = blockIdx.x * 256 + threadIdx.x;
    if (e >= nE) return;
    int d = dst[e];
    int pos = atomicAdd(&cur[d], 1);
    int r = etype[eid[e]];
    epack[off[d] + pos] = src[e] | (r << 28);
}

// ---- gather-aggregate into 4 basis planes, 1/deg folded in ----
__global__ __launch_bounds__(256) void agg_kernel(
    const u16* __restrict__ h, const int* __restrict__ off,
    const int* __restrict__ epack, const float* __restrict__ comp,
    u16* __restrict__ T, int ndst)
{
    __shared__ float cmp[32];
    if (threadIdx.x < 32) cmp[threadIdx.x] = comp[threadIdx.x];
    __syncthreads();
    int row = blockIdx.x * 4 + (threadIdx.x >> 6);
    if (row >= ndst) return;
    int lane = threadIdx.x & 63;
    int beg = off[row], end = off[row + 1];
    float a0[4] = {0.f, 0.f, 0.f, 0.f};
    float a1[4] = {0.f, 0.f, 0.f, 0.f};
    for (int j = beg; j < end; ++j) {
        int v = epack[j];
        int s = v & 0x0FFFFFFF;
        int r = v >> 28;
        unsigned hv = *(const unsigned*)(h + (size_t)s * DD + 2 * lane);
        float x0 = b2f((u16)(hv & 0xffffu));
        float x1 = b2f((u16)(hv >> 16));
        #pragma unroll
        for (int b = 0; b < 4; ++b) {
            float c = cmp[r * 4 + b];
            a0[b] = fmaf(c, x0, a0[b]);
            a1[b] = fmaf(c, x1, a1[b]);
        }
    }
    float inv = 1.f / fmaxf((float)(end - beg), 1.f);
    #pragma unroll
    for (int b = 0; b < 4; ++b) {
        unsigned pk = (unsigned)f2b(a0[b] * inv) | ((unsigned)f2b(a1[b] * inv) << 16);
        *(unsigned*)(T + ((size_t)b * ndst + row) * DD + 2 * lane) = pk;
    }
}

// ---- MFMA GEMM: C[nrows x 128] = sum_p Ap[p] @ Wp[p] + Ar @ Wr + bias ----
// Wt layout: [n][k] bf16 (transposed). A layout: [row][k].
// 16x16x32 bf16 MFMA. A-frag: m=lane&15, k=quad*8+j. C/D: col=lane&15, row=quad*4+reg.
template<bool OBF16, bool RELU, bool AF32>
__global__ __launch_bounds__(256) void mfma_gemm(
    const u16* __restrict__ Ap, int nplanes,
    const void* __restrict__ Ar,
    const u16* __restrict__ Wp, const u16* __restrict__ Wr,
    const float* __restrict__ bias, void* __restrict__ Cv, int nrows)
{
    int wave = threadIdx.x >> 6;
    int lane = threadIdx.x & 63;
    int m0 = blockIdx.x * 64 + wave * 16;
    int ml = lane & 15;
    int q  = lane >> 4;
    int row = m0 + ml;
    bool rv = row < nrows;
    f32x4 acc[8];
    #pragma unroll
    for (int t = 0; t < 8; ++t) acc[t] = (f32x4){0.f, 0.f, 0.f, 0.f};

    for (int p = 0; p < nplanes; ++p) {
        const u16* A = Ap + (size_t)p * nrows * DD;
        const u16* W = Wp + p * 16384;
        #pragma unroll
        for (int kc = 0; kc < 4; ++kc) {
            int k0 = kc * 32 + q * 8;
            bf16x8 af = {0, 0, 0, 0, 0, 0, 0, 0};
            if (rv) af = *(const bf16x8*)(A + (size_t)row * DD + k0);
            #pragma unroll
            for (int t = 0; t < 8; ++t) {
                bf16x8 bf = *(const bf16x8*)(W + (t * 16 + ml) * DD + k0);
                acc[t] = __builtin_amdgcn_mfma_f32_16x16x32_bf16(af, bf, acc[t], 0, 0, 0);
            }
        }
    }
    if (Ar != nullptr) {
        #pragma unroll
        for (int kc = 0; kc < 4; ++kc) {
            int k0 = kc * 32 + q * 8;
            bf16x8 af = {0, 0, 0, 0, 0, 0, 0, 0};
            if (rv) {
                if (AF32) {
                    const float* A = (const float*)Ar + (size_t)row * DD + k0;
                    float4 v0 = *(const float4*)A;
                    float4 v1 = *(const float4*)(A + 4);
                    af[0] = (short)f2b(v0.x); af[1] = (short)f2b(v0.y);
                    af[2] = (short)f2b(v0.z); af[3] = (short)f2b(v0.w);
                    af[4] = (short)f2b(v1.x); af[5] = (short)f2b(v1.y);
                    af[6] = (short)f2b(v1.z); af[7] = (short)f2b(v1.w);
                } else {
                    af = *(const bf16x8*)((const u16*)Ar + (size_t)row * DD + k0);
                }
            }
            #pragma unroll
            for (int t = 0; t < 8; ++t) {
                bf16x8 bf = *(const bf16x8*)(Wr + (t * 16 + ml) * DD + k0);
                acc[t] = __builtin_amdgcn_mfma_f32_16x16x32_bf16(af, bf, acc[t], 0, 0, 0);
            }
        }
    }
    #pragma unroll
    for (int t = 0; t < 8; ++t) {
        int col = t * 16 + ml;
        float bv = bias ? bias[col] : 0.f;
        #pragma unroll
        for (int r2 = 0; r2 < 4; ++r2) {
            int orow = m0 + q * 4 + r2;
            if (orow < nrows) {
                float v = acc[t][r2] + bv;
                if (RELU) v = fmaxf(v, 0.f);
                if (OBF16) ((u16*)Cv)[(size_t)orow * DD + col] = f2b(v);
                else       ((float*)Cv)[(size_t)orow * DD + col] = v;
            }
        }
    }
}

// ---- y = relu(LN(x)*g+b), bf16 in/out, one wave per row ----
__global__ __launch_bounds__(256) void ln_relu_kernel(
    const u16* __restrict__ x, const float* __restrict__ g,
    const float* __restrict__ b, u16* __restrict__ y, int nrows)
{
    int row = blockIdx.x * 4 + (threadIdx.x >> 6);
    if (row >= nrows) return;
    int lane = threadIdx.x & 63;
    unsigned hv = *(const unsigned*)(x + (size_t)row * DD + 2 * lane);
    float v0 = b2f((u16)(hv & 0xffffu));
    float v1 = b2f((u16)(hv >> 16));
    float s = v0 + v1;
    #pragma unroll
    for (int o = 32; o > 0; o >>= 1) s += __shfl_down(s, o);
    s = __shfl(s, 0);
    float mu = s * (1.f / 128.f);
    float d0 = v0 - mu, d1 = v1 - mu;
    float qv = d0 * d0 + d1 * d1;
    #pragma unroll
    for (int o = 32; o > 0; o >>= 1) qv += __shfl_down(qv, o);
    qv = __shfl(qv, 0);
    float rstd = rsqrtf(qv * (1.f / 128.f) + 1e-5f);
    float2 gg = *(const float2*)(g + 2 * lane);
    float2 bb = *(const float2*)(b + 2 * lane);
    float y0 = fmaxf(d0 * rstd * gg.x + bb.x, 0.f);
    float y1 = fmaxf(d1 * rstd * gg.y + bb.y, 0.f);
    unsigned pk = (unsigned)f2b(y0) | ((unsigned)f2b(y1) << 16);
    *(unsigned*)(y + (size_t)row * DD + 2 * lane) = pk;
}

extern "C" void kernel_launch(void* const* d_in, const int* in_sizes, int n_in,
                              void* d_out, int out_size, void* d_ws, size_t ws_size,
                              hipStream_t stream)
{
    const float* x     = (const float*)d_in[0];
    const int* src0    = (const int*)d_in[1];
    const int* dst0    = (const int*)d_in[2];
    const int* eid0    = (const int*)d_in[3];
    const int* src1    = (const int*)d_in[4];
    const int* dst1    = (const int*)d_in[5];
    const int* eid1    = (const int*)d_in[6];
    const int* etype   = (const int*)d_in[7];
    const float* preW  = (const float*)d_in[8];
    const float* preb  = (const float*)d_in[9];
    const float* basis0 = (const float*)d_in[10];
    const float* comp0  = (const float*)d_in[11];
    const float* root0  = (const float*)d_in[12];
    const float* bias0  = (const float*)d_in[13];
    const float* g0    = (const float*)d_in[14];
    const float* be0   = (const float*)d_in[15];
    const float* basis1 = (const float*)d_in[16];
    const float* comp1  = (const float*)d_in[17];
    const float* root1  = (const float*)d_in[18];
    const float* bias1  = (const float*)d_in[19];
    const float* g1    = (const float*)d_in[20];
    const float* be1   = (const float*)d_in[21];
    const float* postW = (const float*)d_in[22];
    const float* postb = (const float*)d_in[23];
    float* out = (float*)d_out;

    const int N0 = 120000, N1 = 30000, N2 = 6000;
    const int E0 = 480000, E1 = 96000;

    char* ws = (char*)d_ws;
    size_t o = 0;
    auto alloc = [&](size_t bytes) { char* p = ws + o; o += (bytes + 255) & ~(size_t)255; return p; };
    u16* h0    = (u16*)alloc((size_t)N0 * DD * 2);
    u16* T0    = (u16*)alloc((size_t)4 * N1 * DD * 2);
    u16* c0    = (u16*)alloc((size_t)N1 * DD * 2);
    u16* h1    = (u16*)alloc((size_t)N1 * DD * 2);
    u16* T1    = (u16*)alloc((size_t)4 * N2 * DD * 2);
    u16* c1    = (u16*)alloc((size_t)N2 * DD * 2);
    u16* h2    = (u16*)alloc((size_t)N2 * DD * 2);
    u16* wt    = (u16*)alloc((size_t)12 * 16384 * 2);
    int* off0  = (int*)alloc((size_t)(N1 + 1) * 4);
    int* off1  = (int*)alloc((size_t)(N2 + 1) * 4);
    int* cntz  = (int*)alloc((size_t)(2 * N1 + 2 * N2) * 4);  // cnt0,cur0,cnt1,cur1
    int* cnt0 = cntz, *cur0 = cntz + N1, *cnt1 = cntz + 2 * N1, *cur1 = cntz + 2 * N1 + N2;
    int* ep0   = (int*)alloc((size_t)E0 * 4);
    int* ep1   = (int*)alloc((size_t)E1 * 4);

    hipMemsetAsync(cntz, 0, (size_t)(2 * N1 + 2 * N2) * 4, stream);

    // weight layout in wt: [0]=pre, [1..4]=basis0, [5]=root0, [6..9]=basis1, [10]=root1, [11]=post
    WtJob job;
    job.src[0] = preW;
    for (int b = 0; b < 4; ++b) job.src[1 + b] = basis0 + (size_t)b * 16384;
    job.src[5] = root0;
    for (int b = 0; b < 4; ++b) job.src[6 + b] = basis1 + (size_t)b * 16384;
    job.src[10] = root1;
    job.src[11] = postW;
    wconv_kernel<<<768, 256, 0, stream>>>(job, wt);

    // CSR build (both layers)
    hist_kernel<<<(E0 + 255) / 256, 256, 0, stream>>>(dst0, cnt0, E0);
    hist_kernel<<<(E1 + 255) / 256, 256, 0, stream>>>(dst1, cnt1, E1);
    scan_kernel<<<1, 1024, 0, stream>>>(cnt0, off0, N1);
    scan_kernel<<<1, 1024, 0, stream>>>(cnt1, off1, N2);
    fill_kernel<<<(E0 + 255) / 256, 256, 0, stream>>>(src0, dst0, eid0, etype, off0, cur0, ep0, E0);
    fill_kernel<<<(E1 + 255) / 256, 256, 0, stream>>>(src1, dst1, eid1, etype, off1, cur1, ep1, E1);

    // h0 = relu(x @ preW + preb)   (f32 A -> bf16 out)
    mfma_gemm<true, true, true><<<(N0 + 63) / 64, 256, 0, stream>>>(
        nullptr, 0, x, nullptr, wt + 0 * 16384, preb, h0, N0);

    // layer 0
    agg_kernel<<<(N1 + 3) / 4, 256, 0, stream>>>(h0, off0, ep0, comp0, T0, N1);
    mfma_gemm<true, false, false><<<(N1 + 63) / 64, 256, 0, stream>>>(
        T0, 4, h0, wt + 1 * 16384, wt + 5 * 16384, bias0, c0, N1);
    ln_relu_kernel<<<(N1 + 3) / 4, 256, 0, stream>>>(c0, g0, be0, h1, N1);

    // layer 1
    agg_kernel<<<(N2 + 3) / 4, 256, 0, stream>>>(h1, off1, ep1, comp1, T1, N2);
    mfma_gemm<true, false, false><<<(N2 + 63) / 64, 256, 0, stream>>>(
        T1, 4, h1, wt + 6 * 16384, wt + 10 * 16384, bias1, c1, N2);
    ln_relu_kernel<<<(N2 + 3) / 4, 256, 0, stream>>>(c1, g1, be1, h2, N2);

    // out = h2 @ postW + postb   (bf16 A -> f32 out)
    mfma_gemm<false, false, false><<<(N2 + 63) / 64, 256, 0, stream>>>(
        nullptr, 0, h2, nullptr, wt + 11 * 16384, postb, out, N2);
}

// Round 3
// 355.516 us; speedup vs baseline: 2.1687x; 1.3070x over previous
//
#include <hip/hip_runtime.h>
#include <cstdint>

#define DD 128

typedef unsigned short u16;
typedef __attribute__((ext_vector_type(8))) short bf16x8;
typedef __attribute__((ext_vector_type(4))) float f32x4;

__device__ __forceinline__ u16 f2b(float f) {
    union { float f; unsigned u; } a; a.f = f;
    unsigned r = (a.u + 0x7fffu + ((a.u >> 16) & 1u)) >> 16;
    return (u16)r;
}
__device__ __forceinline__ float b2f(u16 u) {
    union { unsigned u; float f; } a; a.u = ((unsigned)u) << 16;
    return a.f;
}

// ---- weight convert+transpose: 12 matrices [k][n] f32 -> [n][k] bf16 ----
// LDS-tiled so both global read and write are coalesced.
struct WtJob { const float* src[12]; };
__global__ __launch_bounds__(256) void wconv_kernel(WtJob job, u16* __restrict__ dst)
{
    __shared__ float tile[32][33];
    int m = blockIdx.x >> 4;          // matrix 0..11
    int t = blockIdx.x & 15;          // 4x4 tiles of 32x32
    int tr = (t >> 2) * 32;           // k-base in source
    int tc = (t & 3) * 32;            // n-base in source
    int lx = threadIdx.x & 31, ly = threadIdx.x >> 5;   // 32 x 8
    #pragma unroll
    for (int yy = 0; yy < 32; yy += 8)
        tile[ly + yy][lx] = job.src[m][(tr + ly + yy) * DD + tc + lx];
    __syncthreads();
    #pragma unroll
    for (int yy = 0; yy < 32; yy += 8)
        dst[m * 16384 + (tc + ly + yy) * DD + tr + lx] = f2b(tile[lx][ly + yy]);
}

// ---- CSR build (both layers fused) ----
#define E0C 480000
#define E1C 96000
#define N1C 30000
#define N2C 6000
#define NB0 30
#define NB1 6

__global__ __launch_bounds__(256) void hist_all(
    const int* __restrict__ dst0, const int* __restrict__ dst1,
    int* __restrict__ cnt0, int* __restrict__ cnt1)
{
    int e = blockIdx.x * 256 + threadIdx.x;
    if (e < E0C) atomicAdd(&cnt0[dst0[e]], 1);
    else if (e - E0C < E1C) atomicAdd(&cnt1[dst1[e - E0C]], 1);
}

__global__ __launch_bounds__(1024) void scan_blocks(
    const int* __restrict__ cnt0, const int* __restrict__ cnt1,
    int* __restrict__ off0, int* __restrict__ off1, int* __restrict__ partials)
{
    __shared__ int wsum[16];
    int b = blockIdx.x;
    const int* cnt; int* off; int n, base;
    if (b < NB0) { cnt = cnt0; off = off0; n = N1C; base = b * 1024; }
    else         { cnt = cnt1; off = off1; n = N2C; base = (b - NB0) * 1024; }
    int tid = threadIdx.x, lane = tid & 63, w = tid >> 6;
    int i = base + tid;
    int v = (i < n) ? cnt[i] : 0;
    int s = v;
    #pragma unroll
    for (int o = 1; o < 64; o <<= 1) { int t = __shfl_up(s, o); if (lane >= o) s += t; }
    if (lane == 63) wsum[w] = s;
    __syncthreads();
    if (tid == 0) {
        int run = 0;
        #pragma unroll
        for (int k = 0; k < 16; ++k) { int t2 = wsum[k]; wsum[k] = run; run += t2; }
        partials[b] = run;
    }
    __syncthreads();
    if (i < n) off[i] = wsum[w] + s - v;
}

__global__ void scan_carry(int* __restrict__ partials,
                           int* __restrict__ off0, int* __restrict__ off1)
{
    if (threadIdx.x == 0) {
        int run = 0;
        for (int b = 0; b < NB0; ++b) { int t = partials[b]; partials[b] = run; run += t; }
        off0[N1C] = run;
        run = 0;
        for (int b = NB0; b < NB0 + NB1; ++b) { int t = partials[b]; partials[b] = run; run += t; }
        off1[N2C] = run;
    }
}

__global__ __launch_bounds__(1024) void scan_add(
    const int* __restrict__ partials, int* __restrict__ off0, int* __restrict__ off1)
{
    int b = blockIdx.x;
    int add = partials[b];
    if (b < NB0) { int i = b * 1024 + threadIdx.x; if (i < N1C) off0[i] += add; }
    else         { int i = (b - NB0) * 1024 + threadIdx.x; if (i < N2C) off1[i] += add; }
}

__global__ __launch_bounds__(256) void fill_all(
    const int* __restrict__ src0, const int* __restrict__ dst0, const int* __restrict__ eid0,
    const int* __restrict__ src1, const int* __restrict__ dst1, const int* __restrict__ eid1,
    const int* __restrict__ etype, const int* __restrict__ off0, const int* __restrict__ off1,
    int* __restrict__ cur0, int* __restrict__ cur1,
    int* __restrict__ ep0, int* __restrict__ ep1)
{
    int e = blockIdx.x * 256 + threadIdx.x;
    const int* src; const int* dst; const int* eid; const int* off; int* cur; int* ep;
    if (e < E0C) { src = src0; dst = dst0; eid = eid0; off = off0; cur = cur0; ep = ep0; }
    else {
        e -= E0C;
        if (e >= E1C) return;
        src = src1; dst = dst1; eid = eid1; off = off1; cur = cur1; ep = ep1;
    }
    int d = dst[e];
    int pos = atomicAdd(&cur[d], 1);
    ep[off[d] + pos] = src[e] | (etype[eid[e]] << 28);
}

// ---- gather-aggregate into 4 basis planes, 1/deg folded in, 4-deep MLP ----
__global__ __launch_bounds__(256) void agg_kernel(
    const u16* __restrict__ h, const int* __restrict__ off,
    const int* __restrict__ epack, const float* __restrict__ comp,
    u16* __restrict__ T, int ndst)
{
    __shared__ float cmp[32];
    if (threadIdx.x < 32) cmp[threadIdx.x] = comp[threadIdx.x];
    __syncthreads();
    int row = blockIdx.x * 4 + (threadIdx.x >> 6);
    if (row >= ndst) return;
    int lane = threadIdx.x & 63;
    int beg = off[row], end = off[row + 1];
    float a0[4] = {0.f, 0.f, 0.f, 0.f};
    float a1[4] = {0.f, 0.f, 0.f, 0.f};
    int j = beg;
    for (; j + 4 <= end; j += 4) {
        int v0 = epack[j], v1 = epack[j + 1], v2 = epack[j + 2], v3 = epack[j + 3];
        unsigned g0 = *(const unsigned*)(h + (size_t)(v0 & 0x0FFFFFFF) * DD + 2 * lane);
        unsigned g1 = *(const unsigned*)(h + (size_t)(v1 & 0x0FFFFFFF) * DD + 2 * lane);
        unsigned g2 = *(const unsigned*)(h + (size_t)(v2 & 0x0FFFFFFF) * DD + 2 * lane);
        unsigned g3 = *(const unsigned*)(h + (size_t)(v3 & 0x0FFFFFFF) * DD + 2 * lane);
        int rr[4] = {v0 >> 28, v1 >> 28, v2 >> 28, v3 >> 28};
        unsigned gg[4] = {g0, g1, g2, g3};
        #pragma unroll
        for (int u = 0; u < 4; ++u) {
            float x0 = b2f((u16)(gg[u] & 0xffffu));
            float x1 = b2f((u16)(gg[u] >> 16));
            #pragma unroll
            for (int b = 0; b < 4; ++b) {
                float c = cmp[rr[u] * 4 + b];
                a0[b] = fmaf(c, x0, a0[b]);
                a1[b] = fmaf(c, x1, a1[b]);
            }
        }
    }
    for (; j < end; ++j) {
        int v = epack[j];
        unsigned g = *(const unsigned*)(h + (size_t)(v & 0x0FFFFFFF) * DD + 2 * lane);
        float x0 = b2f((u16)(g & 0xffffu));
        float x1 = b2f((u16)(g >> 16));
        int r = v >> 28;
        #pragma unroll
        for (int b = 0; b < 4; ++b) {
            float c = cmp[r * 4 + b];
            a0[b] = fmaf(c, x0, a0[b]);
            a1[b] = fmaf(c, x1, a1[b]);
        }
    }
    float inv = 1.f / fmaxf((float)(end - beg), 1.f);
    #pragma unroll
    for (int b = 0; b < 4; ++b) {
        unsigned pk = (unsigned)f2b(a0[b] * inv) | ((unsigned)f2b(a1[b] * inv) << 16);
        *(unsigned*)(T + ((size_t)b * ndst + row) * DD + 2 * lane) = pk;
    }
}

// ---- m-blocked MFMA GEMM with optional fused LN+ReLU epilogue ----
// C[nrows x 128] = sum_p Ap[p]@Wp[p] + Ar@Wr + bias, then LN/ReLU per flag.
// Wt layout: [n][k] bf16. A: [row][k]. 16x16x32 bf16 MFMA.
// A-frag: m=lane&15, k=quad*8+j. C/D: col=lane&15, row=quad*4+reg.
template<int MB, bool OBF16, bool RELU, bool AF32, bool LN>
__global__ __launch_bounds__(256) void mfma_gemm(
    const u16* __restrict__ Ap, int nplanes, const void* __restrict__ Ar,
    const u16* __restrict__ Wp, const u16* __restrict__ Wr,
    const float* __restrict__ bias, const float* __restrict__ gw,
    const float* __restrict__ bw, void* __restrict__ Cv, int nrows)
{
    int wave = threadIdx.x >> 6;
    int lane = threadIdx.x & 63;
    int ml = lane & 15, q = lane >> 4;
    int mbase = blockIdx.x * (64 * MB) + wave * (16 * MB);
    f32x4 acc[MB][8];
    #pragma unroll
    for (int mt = 0; mt < MB; ++mt)
        #pragma unroll
        for (int t = 0; t < 8; ++t) acc[mt][t] = (f32x4){0.f, 0.f, 0.f, 0.f};

    for (int p = 0; p < nplanes + 1; ++p) {
        bool isroot = (p == nplanes);
        const u16* A = isroot ? (const u16*)Ar : Ap + (size_t)p * nrows * DD;
        const u16* W = isroot ? Wr : Wp + p * 16384;
        #pragma unroll
        for (int kc = 0; kc < 4; ++kc) {
            int k0 = kc * 32 + q * 8;
            bf16x8 bfr[8];
            #pragma unroll
            for (int t = 0; t < 8; ++t)
                bfr[t] = *(const bf16x8*)(W + (t * 16 + ml) * DD + k0);
            #pragma unroll
            for (int mt = 0; mt < MB; ++mt) {
                int row = mbase + mt * 16 + ml;
                bf16x8 af = (bf16x8){0, 0, 0, 0, 0, 0, 0, 0};
                if (row < nrows) {
                    if (AF32 && isroot) {
                        const float* Aq = (const float*)Ar + (size_t)row * DD + k0;
                        float4 u0 = *(const float4*)Aq;
                        float4 u1 = *(const float4*)(Aq + 4);
                        af[0] = (short)f2b(u0.x); af[1] = (short)f2b(u0.y);
                        af[2] = (short)f2b(u0.z); af[3] = (short)f2b(u0.w);
                        af[4] = (short)f2b(u1.x); af[5] = (short)f2b(u1.y);
                        af[6] = (short)f2b(u1.z); af[7] = (short)f2b(u1.w);
                    } else {
                        af = *(const bf16x8*)(A + (size_t)row * DD + k0);
                    }
                }
                #pragma unroll
                for (int t = 0; t < 8; ++t)
                    acc[mt][t] = __builtin_amdgcn_mfma_f32_16x16x32_bf16(af, bfr[t], acc[mt][t], 0, 0, 0);
            }
        }
    }

    float bb[8];
    #pragma unroll
    for (int t = 0; t < 8; ++t) bb[t] = bias[t * 16 + ml];
    float gg[8], ww[8];
    if (LN) {
        #pragma unroll
        for (int t = 0; t < 8; ++t) { gg[t] = gw[t * 16 + ml]; ww[t] = bw[t * 16 + ml]; }
    }

    #pragma unroll
    for (int mt = 0; mt < MB; ++mt) {
        #pragma unroll
        for (int r2 = 0; r2 < 4; ++r2) {
            int row = mbase + mt * 16 + q * 4 + r2;   // uniform across the 16-lane quad
            if (row >= nrows) continue;
            float v[8];
            #pragma unroll
            for (int t = 0; t < 8; ++t) v[t] = acc[mt][t][r2] + bb[t];
            if (LN) {
                float s1 = 0.f, s2 = 0.f;
                #pragma unroll
                for (int t = 0; t < 8; ++t) { s1 += v[t]; s2 += v[t] * v[t]; }
                #pragma unroll
                for (int o = 1; o < 16; o <<= 1) {
                    s1 += __shfl_xor(s1, o);
                    s2 += __shfl_xor(s2, o);
                }
                float mu = s1 * (1.f / 128.f);
                float var = s2 * (1.f / 128.f) - mu * mu;
                float rstd = rsqrtf(fmaxf(var, 0.f) + 1e-5f);
                #pragma unroll
                for (int t = 0; t < 8; ++t) v[t] = (v[t] - mu) * rstd * gg[t] + ww[t];
            }
            if (RELU || LN) {
                #pragma unroll
                for (int t = 0; t < 8; ++t) v[t] = fmaxf(v[t], 0.f);
            }
            #pragma unroll
            for (int t = 0; t < 8; ++t) {
                if (OBF16) ((u16*)Cv)[(size_t)row * DD + t * 16 + ml] = f2b(v[t]);
                else       ((float*)Cv)[(size_t)row * DD + t * 16 + ml] = v[t];
            }
        }
    }
}

extern "C" void kernel_launch(void* const* d_in, const int* in_sizes, int n_in,
                              void* d_out, int out_size, void* d_ws, size_t ws_size,
                              hipStream_t stream)
{
    const float* x     = (const float*)d_in[0];
    const int* src0    = (const int*)d_in[1];
    const int* dst0    = (const int*)d_in[2];
    const int* eid0    = (const int*)d_in[3];
    const int* src1    = (const int*)d_in[4];
    const int* dst1    = (const int*)d_in[5];
    const int* eid1    = (const int*)d_in[6];
    const int* etype   = (const int*)d_in[7];
    const float* preW  = (const float*)d_in[8];
    const float* preb  = (const float*)d_in[9];
    const float* basis0 = (const float*)d_in[10];
    const float* comp0  = (const float*)d_in[11];
    const float* root0  = (const float*)d_in[12];
    const float* bias0  = (const float*)d_in[13];
    const float* g0    = (const float*)d_in[14];
    const float* be0   = (const float*)d_in[15];
    const float* basis1 = (const float*)d_in[16];
    const float* comp1  = (const float*)d_in[17];
    const float* root1  = (const float*)d_in[18];
    const float* bias1  = (const float*)d_in[19];
    const float* g1    = (const float*)d_in[20];
    const float* be1   = (const float*)d_in[21];
    const float* postW = (const float*)d_in[22];
    const float* postb = (const float*)d_in[23];
    float* out = (float*)d_out;

    const int N0 = 120000, N1 = N1C, N2 = N2C;
    const int E0 = E0C, E1 = E1C;

    char* ws = (char*)d_ws;
    size_t o = 0;
    auto alloc = [&](size_t bytes) { char* p = ws + o; o += (bytes + 255) & ~(size_t)255; return p; };
    u16* h0    = (u16*)alloc((size_t)N0 * DD * 2);
    u16* T0    = (u16*)alloc((size_t)4 * N1 * DD * 2);
    u16* h1    = (u16*)alloc((size_t)N1 * DD * 2);
    u16* T1    = (u16*)alloc((size_t)4 * N2 * DD * 2);
    u16* h2    = (u16*)alloc((size_t)N2 * DD * 2);
    u16* wt    = (u16*)alloc((size_t)12 * 16384 * 2);
    int* off0  = (int*)alloc((size_t)(N1 + 1) * 4);
    int* off1  = (int*)alloc((size_t)(N2 + 1) * 4);
    int* cntz  = (int*)alloc((size_t)(2 * N1 + 2 * N2) * 4);
    int* cnt0 = cntz, *cur0 = cntz + N1, *cnt1 = cntz + 2 * N1, *cur1 = cntz + 2 * N1 + N2;
    int* ep0   = (int*)alloc((size_t)E0 * 4);
    int* ep1   = (int*)alloc((size_t)E1 * 4);
    int* partials = (int*)alloc(64 * 4);

    hipMemsetAsync(cntz, 0, (size_t)(2 * N1 + 2 * N2) * 4, stream);

    // wt layout: [0]=pre, [1..4]=basis0, [5]=root0, [6..9]=basis1, [10]=root1, [11]=post
    WtJob job;
    job.src[0] = preW;
    for (int b = 0; b < 4; ++b) job.src[1 + b] = basis0 + (size_t)b * 16384;
    job.src[5] = root0;
    for (int b = 0; b < 4; ++b) job.src[6 + b] = basis1 + (size_t)b * 16384;
    job.src[10] = root1;
    job.src[11] = postW;
    wconv_kernel<<<192, 256, 0, stream>>>(job, wt);

    // CSR build
    hist_all<<<(E0 + E1 + 255) / 256, 256, 0, stream>>>(dst0, dst1, cnt0, cnt1);
    scan_blocks<<<NB0 + NB1, 1024, 0, stream>>>(cnt0, cnt1, off0, off1, partials);
    scan_carry<<<1, 64, 0, stream>>>(partials, off0, off1);
    scan_add<<<NB0 + NB1, 1024, 0, stream>>>(partials, off0, off1);
    fill_all<<<(E0 + E1 + 255) / 256, 256, 0, stream>>>(
        src0, dst0, eid0, src1, dst1, eid1, etype, off0, off1, cur0, cur1, ep0, ep1);

    // h0 = relu(x @ preW + preb)
    mfma_gemm<4, true, true, true, false><<<(N0 + 255) / 256, 256, 0, stream>>>(
        nullptr, 0, x, nullptr, wt + 0 * 16384, preb, nullptr, nullptr, h0, N0);

    // layer 0: gather-agg + conv GEMM with fused LN+ReLU
    agg_kernel<<<(N1 + 3) / 4, 256, 0, stream>>>(h0, off0, ep0, comp0, T0, N1);
    mfma_gemm<4, true, false, false, true><<<(N1 + 255) / 256, 256, 0, stream>>>(
        T0, 4, h0, wt + 1 * 16384, wt + 5 * 16384, bias0, g0, be0, h1, N1);

    // layer 1
    agg_kernel<<<(N2 + 3) / 4, 256, 0, stream>>>(h1, off1, ep1, comp1, T1, N2);
    mfma_gemm<1, true, false, false, true><<<(N2 + 63) / 64, 256, 0, stream>>>(
        T1, 4, h1, wt + 6 * 16384, wt + 10 * 16384, bias1, g1, be1, h2, N2);

    // out = h2 @ postW + postb
    mfma_gemm<1, false, false, false, false><<<(N2 + 63) / 64, 256, 0, stream>>>(
        nullptr, 0, h2, nullptr, wt + 11 * 16384, postb, nullptr, nullptr, out, N2);
}

// Round 4
// 342.637 us; speedup vs baseline: 2.2503x; 1.0376x over previous
//
#include <hip/hip_runtime.h>
#include <cstdint>

#define DD 128

typedef unsigned short u16;
typedef __attribute__((ext_vector_type(8))) short bf16x8;
typedef __attribute__((ext_vector_type(16))) float f32x16;

__device__ __forceinline__ u16 f2b(float f) {
    union { float f; unsigned u; } a; a.f = f;
    unsigned r = (a.u + 0x7fffu + ((a.u >> 16) & 1u)) >> 16;
    return (u16)r;
}
__device__ __forceinline__ float b2f(u16 u) {
    union { unsigned u; float f; } a; a.u = ((unsigned)u) << 16;
    return a.f;
}

// ---- weight convert+transpose: 12 matrices [k][n] f32 -> [n][k] bf16 ----
struct WtJob { const float* src[12]; };
__global__ __launch_bounds__(256) void wconv_kernel(WtJob job, u16* __restrict__ dst)
{
    __shared__ float tile[32][33];
    int m = blockIdx.x >> 4;
    int t = blockIdx.x & 15;
    int tr = (t >> 2) * 32;
    int tc = (t & 3) * 32;
    int lx = threadIdx.x & 31, ly = threadIdx.x >> 5;
    #pragma unroll
    for (int yy = 0; yy < 32; yy += 8)
        tile[ly + yy][lx] = job.src[m][(tr + ly + yy) * DD + tc + lx];
    __syncthreads();
    #pragma unroll
    for (int yy = 0; yy < 32; yy += 8)
        dst[m * 16384 + (tc + ly + yy) * DD + tr + lx] = f2b(tile[lx][ly + yy]);
}

// ---- CSR build ----
#define E0C 480000
#define E1C 96000
#define N1C 30000
#define N2C 6000
#define NB0 30
#define NB1 6

__global__ __launch_bounds__(256) void hist_all(
    const int* __restrict__ dst0, const int* __restrict__ dst1,
    int* __restrict__ cnt0, int* __restrict__ cnt1)
{
    int e = blockIdx.x * 256 + threadIdx.x;
    if (e < E0C) atomicAdd(&cnt0[dst0[e]], 1);
    else if (e - E0C < E1C) atomicAdd(&cnt1[dst1[e - E0C]], 1);
}

__global__ __launch_bounds__(1024) void scan_blocks(
    const int* __restrict__ cnt0, const int* __restrict__ cnt1,
    int* __restrict__ off0, int* __restrict__ off1, int* __restrict__ partials)
{
    __shared__ int wsum[16];
    int b = blockIdx.x;
    const int* cnt; int* off; int n, base;
    if (b < NB0) { cnt = cnt0; off = off0; n = N1C; base = b * 1024; }
    else         { cnt = cnt1; off = off1; n = N2C; base = (b - NB0) * 1024; }
    int tid = threadIdx.x, lane = tid & 63, w = tid >> 6;
    int i = base + tid;
    int v = (i < n) ? cnt[i] : 0;
    int s = v;
    #pragma unroll
    for (int o = 1; o < 64; o <<= 1) { int t = __shfl_up(s, o); if (lane >= o) s += t; }
    if (lane == 63) wsum[w] = s;
    __syncthreads();
    if (tid == 0) {
        int run = 0;
        #pragma unroll
        for (int k = 0; k < 16; ++k) { int t2 = wsum[k]; wsum[k] = run; run += t2; }
        partials[b] = run;
    }
    __syncthreads();
    if (i < n) off[i] = wsum[w] + s - v;
}

__global__ void scan_carry(int* __restrict__ partials,
                           int* __restrict__ off0, int* __restrict__ off1)
{
    if (threadIdx.x == 0) {
        int run = 0;
        for (int b = 0; b < NB0; ++b) { int t = partials[b]; partials[b] = run; run += t; }
        off0[N1C] = run;
        run = 0;
        for (int b = NB0; b < NB0 + NB1; ++b) { int t = partials[b]; partials[b] = run; run += t; }
        off1[N2C] = run;
    }
}

__global__ __launch_bounds__(1024) void scan_add(
    const int* __restrict__ partials, int* __restrict__ off0, int* __restrict__ off1)
{
    int b = blockIdx.x;
    int add = partials[b];
    if (b < NB0) { int i = b * 1024 + threadIdx.x; if (i < N1C) off0[i] += add; }
    else         { int i = (b - NB0) * 1024 + threadIdx.x; if (i < N2C) off1[i] += add; }
}

__global__ __launch_bounds__(256) void fill_all(
    const int* __restrict__ src0, const int* __restrict__ dst0, const int* __restrict__ eid0,
    const int* __restrict__ src1, const int* __restrict__ dst1, const int* __restrict__ eid1,
    const int* __restrict__ etype, const int* __restrict__ off0, const int* __restrict__ off1,
    int* __restrict__ cur0, int* __restrict__ cur1,
    int* __restrict__ ep0, int* __restrict__ ep1)
{
    int e = blockIdx.x * 256 + threadIdx.x;
    const int* src; const int* dst; const int* eid; const int* off; int* cur; int* ep;
    if (e < E0C) { src = src0; dst = dst0; eid = eid0; off = off0; cur = cur0; ep = ep0; }
    else {
        e -= E0C;
        if (e >= E1C) return;
        src = src1; dst = dst1; eid = eid1; off = off1; cur = cur1; ep = ep1;
    }
    int d = dst[e];
    int pos = atomicAdd(&cur[d], 1);
    ep[off[d] + pos] = src[e] | (etype[eid[e]] << 28);
}

// ---- gather-aggregate into 4 basis planes, 1/deg folded in, 8-deep MLP ----
__global__ __launch_bounds__(256) void agg_kernel(
    const u16* __restrict__ h, const int* __restrict__ off,
    const int* __restrict__ epack, const float* __restrict__ comp,
    u16* __restrict__ T, int ndst)
{
    __shared__ float4 cmp4[8];
    if (threadIdx.x < 8) {
        const float4* c = (const float4*)comp;
        cmp4[threadIdx.x] = c[threadIdx.x];
    }
    __syncthreads();
    int row = blockIdx.x * 4 + (threadIdx.x >> 6);
    if (row >= ndst) return;
    int lane = threadIdx.x & 63;
    int beg = off[row], end = off[row + 1];
    float a0[4] = {0.f, 0.f, 0.f, 0.f};
    float a1[4] = {0.f, 0.f, 0.f, 0.f};
    int j = beg;
    for (; j + 8 <= end; j += 8) {
        int vv[8]; unsigned gg[8];
        #pragma unroll
        for (int u = 0; u < 8; ++u) vv[u] = epack[j + u];
        #pragma unroll
        for (int u = 0; u < 8; ++u)
            gg[u] = *(const unsigned*)(h + (size_t)(vv[u] & 0x0FFFFFFF) * DD + 2 * lane);
        #pragma unroll
        for (int u = 0; u < 8; ++u) {
            float4 c = cmp4[vv[u] >> 28];
            float x0 = b2f((u16)(gg[u] & 0xffffu));
            float x1 = b2f((u16)(gg[u] >> 16));
            a0[0] = fmaf(c.x, x0, a0[0]); a1[0] = fmaf(c.x, x1, a1[0]);
            a0[1] = fmaf(c.y, x0, a0[1]); a1[1] = fmaf(c.y, x1, a1[1]);
            a0[2] = fmaf(c.z, x0, a0[2]); a1[2] = fmaf(c.z, x1, a1[2]);
            a0[3] = fmaf(c.w, x0, a0[3]); a1[3] = fmaf(c.w, x1, a1[3]);
        }
    }
    for (; j < end; ++j) {
        int v = epack[j];
        unsigned g = *(const unsigned*)(h + (size_t)(v & 0x0FFFFFFF) * DD + 2 * lane);
        float4 c = cmp4[v >> 28];
        float x0 = b2f((u16)(g & 0xffffu));
        float x1 = b2f((u16)(g >> 16));
        a0[0] = fmaf(c.x, x0, a0[0]); a1[0] = fmaf(c.x, x1, a1[0]);
        a0[1] = fmaf(c.y, x0, a0[1]); a1[1] = fmaf(c.y, x1, a1[1]);
        a0[2] = fmaf(c.z, x0, a0[2]); a1[2] = fmaf(c.z, x1, a1[2]);
        a0[3] = fmaf(c.w, x0, a0[3]); a1[3] = fmaf(c.w, x1, a1[3]);
    }
    float inv = 1.f / fmaxf((float)(end - beg), 1.f);
    #pragma unroll
    for (int b = 0; b < 4; ++b) {
        unsigned pk = (unsigned)f2b(a0[b] * inv) | ((unsigned)f2b(a1[b] * inv) << 16);
        *(unsigned*)(T + ((size_t)b * ndst + row) * DD + 2 * lane) = pk;
    }
}

// ---- 32x32x16 MFMA GEMM, one 32-row m-tile per wave ----
// C[nrows x 128] = sum_p Ap[p]@Wp[p] + Ar@Wr + bias, optional LN/ReLU.
// Wt layout: [n][k] bf16. A: [row][k].
// A-frag: m=lane&31, k=(lane>>5)*8+j. B-frag mirrors. C/D: col=lane&31,
// row=(reg&3)+8*(reg>>2)+4*(lane>>5)  [measured: learn_hip m74/m101].
template<int WPB, bool OBF16, bool RELU, bool AF32, bool LN>
__global__ __launch_bounds__(WPB * 64) void mfma_gemm(
    const u16* __restrict__ Ap, int nplanes, const void* __restrict__ Ar,
    const u16* __restrict__ Wp, const u16* __restrict__ Wr,
    const float* __restrict__ bias, const float* __restrict__ gw,
    const float* __restrict__ bw, void* __restrict__ Cv, int nrows)
{
    int wave = threadIdx.x >> 6;
    int lane = threadIdx.x & 63;
    int l31 = lane & 31, half = lane >> 5;
    int m0 = (blockIdx.x * WPB + wave) * 32;
    int arow = m0 + l31;
    bool rv = arow < nrows;
    f32x16 acc[4];
    #pragma unroll
    for (int t = 0; t < 4; ++t)
        #pragma unroll
        for (int i = 0; i < 16; ++i) acc[t][i] = 0.f;

    for (int p = 0; p < nplanes + 1; ++p) {
        bool isroot = (p == nplanes);
        const u16* A = isroot ? (const u16*)Ar : Ap + (size_t)p * nrows * DD;
        const u16* W = isroot ? Wr : Wp + p * 16384;
        #pragma unroll
        for (int kc = 0; kc < 8; ++kc) {
            int ko = kc * 16 + half * 8;
            bf16x8 bfr[4];
            #pragma unroll
            for (int t = 0; t < 4; ++t)
                bfr[t] = *(const bf16x8*)(W + (size_t)(t * 32 + l31) * DD + ko);
            bf16x8 af = (bf16x8){0, 0, 0, 0, 0, 0, 0, 0};
            if (rv) {
                if (AF32 && isroot) {
                    const float* Aq = (const float*)Ar + (size_t)arow * DD + ko;
                    float4 u0 = *(const float4*)Aq;
                    float4 u1 = *(const float4*)(Aq + 4);
                    af[0] = (short)f2b(u0.x); af[1] = (short)f2b(u0.y);
                    af[2] = (short)f2b(u0.z); af[3] = (short)f2b(u0.w);
                    af[4] = (short)f2b(u1.x); af[5] = (short)f2b(u1.y);
                    af[6] = (short)f2b(u1.z); af[7] = (short)f2b(u1.w);
                } else {
                    af = *(const bf16x8*)(A + (size_t)arow * DD + ko);
                }
            }
            #pragma unroll
            for (int t = 0; t < 4; ++t)
                acc[t] = __builtin_amdgcn_mfma_f32_32x32x16_bf16(af, bfr[t], acc[t], 0, 0, 0);
        }
    }

    float bb[4];
    #pragma unroll
    for (int t = 0; t < 4; ++t) bb[t] = bias[t * 32 + l31];
    float gg[4], ww[4];
    if (LN) {
        #pragma unroll
        for (int t = 0; t < 4; ++t) { gg[t] = gw[t * 32 + l31]; ww[t] = bw[t * 32 + l31]; }
    }

    #pragma unroll
    for (int reg = 0; reg < 16; ++reg) {
        int rl = (reg & 3) + 8 * (reg >> 2) + 4 * half;
        int row = m0 + rl;
        float v[4];
        #pragma unroll
        for (int t = 0; t < 4; ++t) v[t] = acc[t][reg] + bb[t];
        if (LN) {
            float s1 = 0.f, s2 = 0.f;
            #pragma unroll
            for (int t = 0; t < 4; ++t) { s1 += v[t]; s2 += v[t] * v[t]; }
            #pragma unroll
            for (int o = 1; o < 32; o <<= 1) {
                s1 += __shfl_xor(s1, o);
                s2 += __shfl_xor(s2, o);
            }
            float mu = s1 * (1.f / 128.f);
            float var = s2 * (1.f / 128.f) - mu * mu;
            float rstd = rsqrtf(fmaxf(var, 0.f) + 1e-5f);
            #pragma unroll
            for (int t = 0; t < 4; ++t) v[t] = (v[t] - mu) * rstd * gg[t] + ww[t];
        }
        if (RELU || LN) {
            #pragma unroll
            for (int t = 0; t < 4; ++t) v[t] = fmaxf(v[t], 0.f);
        }
        if (row < nrows) {
            #pragma unroll
            for (int t = 0; t < 4; ++t) {
                if (OBF16) ((u16*)Cv)[(size_t)row * DD + t * 32 + l31] = f2b(v[t]);
                else       ((float*)Cv)[(size_t)row * DD + t * 32 + l31] = v[t];
            }
        }
    }
}

extern "C" void kernel_launch(void* const* d_in, const int* in_sizes, int n_in,
                              void* d_out, int out_size, void* d_ws, size_t ws_size,
                              hipStream_t stream)
{
    const float* x     = (const float*)d_in[0];
    const int* src0    = (const int*)d_in[1];
    const int* dst0    = (const int*)d_in[2];
    const int* eid0    = (const int*)d_in[3];
    const int* src1    = (const int*)d_in[4];
    const int* dst1    = (const int*)d_in[5];
    const int* eid1    = (const int*)d_in[6];
    const int* etype   = (const int*)d_in[7];
    const float* preW  = (const float*)d_in[8];
    const float* preb  = (const float*)d_in[9];
    const float* basis0 = (const float*)d_in[10];
    const float* comp0  = (const float*)d_in[11];
    const float* root0  = (const float*)d_in[12];
    const float* bias0  = (const float*)d_in[13];
    const float* g0    = (const float*)d_in[14];
    const float* be0   = (const float*)d_in[15];
    const float* basis1 = (const float*)d_in[16];
    const float* comp1  = (const float*)d_in[17];
    const float* root1  = (const float*)d_in[18];
    const float* bias1  = (const float*)d_in[19];
    const float* g1    = (const float*)d_in[20];
    const float* be1   = (const float*)d_in[21];
    const float* postW = (const float*)d_in[22];
    const float* postb = (const float*)d_in[23];
    float* out = (float*)d_out;

    const int N0 = 120000, N1 = N1C, N2 = N2C;
    const int E0 = E0C, E1 = E1C;

    char* ws = (char*)d_ws;
    size_t o = 0;
    auto alloc = [&](size_t bytes) { char* p = ws + o; o += (bytes + 255) & ~(size_t)255; return p; };
    u16* h0    = (u16*)alloc((size_t)N0 * DD * 2);
    u16* T0    = (u16*)alloc((size_t)4 * N1 * DD * 2);
    u16* h1    = (u16*)alloc((size_t)N1 * DD * 2);
    u16* T1    = (u16*)alloc((size_t)4 * N2 * DD * 2);
    u16* h2    = (u16*)alloc((size_t)N2 * DD * 2);
    u16* wt    = (u16*)alloc((size_t)12 * 16384 * 2);
    int* off0  = (int*)alloc((size_t)(N1 + 1) * 4);
    int* off1  = (int*)alloc((size_t)(N2 + 1) * 4);
    int* cntz  = (int*)alloc((size_t)(2 * N1 + 2 * N2) * 4);
    int* cnt0 = cntz, *cur0 = cntz + N1, *cnt1 = cntz + 2 * N1, *cur1 = cntz + 2 * N1 + N2;
    int* ep0   = (int*)alloc((size_t)E0 * 4);
    int* ep1   = (int*)alloc((size_t)E1 * 4);
    int* partials = (int*)alloc(64 * 4);

    hipMemsetAsync(cntz, 0, (size_t)(2 * N1 + 2 * N2) * 4, stream);

    // wt layout: [0]=pre, [1..4]=basis0, [5]=root0, [6..9]=basis1, [10]=root1, [11]=post
    WtJob job;
    job.src[0] = preW;
    for (int b = 0; b < 4; ++b) job.src[1 + b] = basis0 + (size_t)b * 16384;
    job.src[5] = root0;
    for (int b = 0; b < 4; ++b) job.src[6 + b] = basis1 + (size_t)b * 16384;
    job.src[10] = root1;
    job.src[11] = postW;
    wconv_kernel<<<192, 256, 0, stream>>>(job, wt);

    // CSR build
    hist_all<<<(E0 + E1 + 255) / 256, 256, 0, stream>>>(dst0, dst1, cnt0, cnt1);
    scan_blocks<<<NB0 + NB1, 1024, 0, stream>>>(cnt0, cnt1, off0, off1, partials);
    scan_carry<<<1, 64, 0, stream>>>(partials, off0, off1);
    scan_add<<<NB0 + NB1, 1024, 0, stream>>>(partials, off0, off1);
    fill_all<<<(E0 + E1 + 255) / 256, 256, 0, stream>>>(
        src0, dst0, eid0, src1, dst1, eid1, etype, off0, off1, cur0, cur1, ep0, ep1);

    // h0 = relu(x @ preW + preb)   (938 blocks x 4 waves, 128 rows/block)
    mfma_gemm<4, true, true, true, false><<<(N0 + 127) / 128, 256, 0, stream>>>(
        nullptr, 0, x, nullptr, wt + 0 * 16384, preb, nullptr, nullptr, h0, N0);

    // layer 0: gather-agg + conv GEMM with fused LN+ReLU (938 single-wave blocks)
    agg_kernel<<<(N1 + 3) / 4, 256, 0, stream>>>(h0, off0, ep0, comp0, T0, N1);
    mfma_gemm<1, true, false, false, true><<<(N1 + 31) / 32, 64, 0, stream>>>(
        T0, 4, h0, wt + 1 * 16384, wt + 5 * 16384, bias0, g0, be0, h1, N1);

    // layer 1
    agg_kernel<<<(N2 + 3) / 4, 256, 0, stream>>>(h1, off1, ep1, comp1, T1, N2);
    mfma_gemm<1, true, false, false, true><<<(N2 + 31) / 32, 64, 0, stream>>>(
        T1, 4, h1, wt + 6 * 16384, wt + 10 * 16384, bias1, g1, be1, h2, N2);

    // out = h2 @ postW + postb
    mfma_gemm<1, false, false, false, false><<<(N2 + 31) / 32, 64, 0, stream>>>(
        nullptr, 0, h2, nullptr, wt + 11 * 16384, postb, nullptr, nullptr, out, N2);
}

// Round 5
// 336.558 us; speedup vs baseline: 2.2909x; 1.0181x over previous
//
#include <hip/hip_runtime.h>
#include <cstdint>

#define DD 128

typedef unsigned short u16;
typedef __attribute__((ext_vector_type(8))) short bf16x8;
typedef __attribute__((ext_vector_type(16))) float f32x16;

__device__ __forceinline__ u16 f2b(float f) {
    union { float f; unsigned u; } a; a.f = f;
    unsigned r = (a.u + 0x7fffu + ((a.u >> 16) & 1u)) >> 16;
    return (u16)r;
}
__device__ __forceinline__ float b2f(u16 u) {
    union { unsigned u; float f; } a; a.u = ((unsigned)u) << 16;
    return a.f;
}

// ---- weight convert+transpose into MFMA fragment order ----
// src: [k][n] f32 row-major. dst (shorts): mat*16384 + kc*2048 + t*512 +
// half*256 + l31*8 + j  where n = t*32+l31, k = kc*16+half*8+j.
// In the GEMM, B-frag (t,kc) for lane is one bf16x8 at
// mat_base + ((kc*4+t)*64 + lane)*8  -> lane-consecutive 16B: perfect coalescing.
struct WtJob { const float* src[12]; };
__global__ __launch_bounds__(256) void wconv_kernel(WtJob job, u16* __restrict__ dst)
{
    __shared__ float tile[32][33];
    int m = blockIdx.x >> 4;
    int t4 = blockIdx.x & 15;
    int tr = (t4 >> 2) * 32;   // k-base
    int tc = (t4 & 3) * 32;    // n-base
    int lx = threadIdx.x & 31, ly = threadIdx.x >> 5;
    #pragma unroll
    for (int yy = 0; yy < 32; yy += 8)
        tile[ly + yy][lx] = job.src[m][(tr + ly + yy) * DD + tc + lx];
    __syncthreads();
    int tid = threadIdx.x;
    if (tid < 128) {
        int nl = tid >> 2;              // 0..31 (n within tile)
        int kch = tid & 3;              // 0..3  (8-wide k chunk)
        int k = tr + kch * 8;
        int n = tc + nl;
        int kc = k >> 4, half = (k >> 3) & 1;
        int t = n >> 5, l31 = n & 31;
        bf16x8 pk;
        #pragma unroll
        for (int j = 0; j < 8; ++j) pk[j] = (short)f2b(tile[kch * 8 + j][nl]);
        *(bf16x8*)(dst + (size_t)m * 16384 + kc * 2048 + t * 512 + half * 256 + l31 * 8) = pk;
    }
}

// ---- CSR build ----
#define E0C 480000
#define E1C 96000
#define N1C 30000
#define N2C 6000
#define NB0 30
#define NB1 6

__global__ __launch_bounds__(256) void hist_all(
    const int* __restrict__ dst0, const int* __restrict__ dst1,
    int* __restrict__ cnt0, int* __restrict__ cnt1)
{
    int e = blockIdx.x * 256 + threadIdx.x;
    if (e < E0C) atomicAdd(&cnt0[dst0[e]], 1);
    else if (e - E0C < E1C) atomicAdd(&cnt1[dst1[e - E0C]], 1);
}

__global__ __launch_bounds__(1024) void scan_blocks(
    const int* __restrict__ cnt0, const int* __restrict__ cnt1,
    int* __restrict__ off0, int* __restrict__ off1, int* __restrict__ partials)
{
    __shared__ int wsum[16];
    int b = blockIdx.x;
    const int* cnt; int* off; int n, base;
    if (b < NB0) { cnt = cnt0; off = off0; n = N1C; base = b * 1024; }
    else         { cnt = cnt1; off = off1; n = N2C; base = (b - NB0) * 1024; }
    int tid = threadIdx.x, lane = tid & 63, w = tid >> 6;
    int i = base + tid;
    int v = (i < n) ? cnt[i] : 0;
    int s = v;
    #pragma unroll
    for (int o = 1; o < 64; o <<= 1) { int t = __shfl_up(s, o); if (lane >= o) s += t; }
    if (lane == 63) wsum[w] = s;
    __syncthreads();
    if (tid == 0) {
        int run = 0;
        #pragma unroll
        for (int k = 0; k < 16; ++k) { int t2 = wsum[k]; wsum[k] = run; run += t2; }
        partials[b] = run;
    }
    __syncthreads();
    if (i < n) off[i] = wsum[w] + s - v;
}

__global__ void scan_carry(int* __restrict__ partials,
                           int* __restrict__ off0, int* __restrict__ off1)
{
    if (threadIdx.x == 0) {
        int run = 0;
        for (int b = 0; b < NB0; ++b) { int t = partials[b]; partials[b] = run; run += t; }
        off0[N1C] = run;
        run = 0;
        for (int b = NB0; b < NB0 + NB1; ++b) { int t = partials[b]; partials[b] = run; run += t; }
        off1[N2C] = run;
    }
}

__global__ __launch_bounds__(1024) void scan_add(
    const int* __restrict__ partials, int* __restrict__ off0, int* __restrict__ off1)
{
    int b = blockIdx.x;
    int add = partials[b];
    if (b < NB0) { int i = b * 1024 + threadIdx.x; if (i < N1C) off0[i] += add; }
    else         { int i = (b - NB0) * 1024 + threadIdx.x; if (i < N2C) off1[i] += add; }
}

__global__ __launch_bounds__(256) void fill_all(
    const int* __restrict__ src0, const int* __restrict__ dst0, const int* __restrict__ eid0,
    const int* __restrict__ src1, const int* __restrict__ dst1, const int* __restrict__ eid1,
    const int* __restrict__ etype, const int* __restrict__ off0, const int* __restrict__ off1,
    int* __restrict__ cur0, int* __restrict__ cur1,
    int* __restrict__ ep0, int* __restrict__ ep1)
{
    int e = blockIdx.x * 256 + threadIdx.x;
    const int* src; const int* dst; const int* eid; const int* off; int* cur; int* ep;
    if (e < E0C) { src = src0; dst = dst0; eid = eid0; off = off0; cur = cur0; ep = ep0; }
    else {
        e -= E0C;
        if (e >= E1C) return;
        src = src1; dst = dst1; eid = eid1; off = off1; cur = cur1; ep = ep1;
    }
    int d = dst[e];
    int pos = atomicAdd(&cur[d], 1);
    ep[off[d] + pos] = src[e] | (etype[eid[e]] << 28);
}

// ---- gather-aggregate into 4 basis planes, 1/deg folded in ----
__global__ __launch_bounds__(256) void agg_kernel(
    const u16* __restrict__ h, const int* __restrict__ off,
    const int* __restrict__ epack, const float* __restrict__ comp,
    u16* __restrict__ T, int ndst)
{
    __shared__ float4 cmp4[8];
    if (threadIdx.x < 8) {
        const float4* c = (const float4*)comp;
        cmp4[threadIdx.x] = c[threadIdx.x];
    }
    __syncthreads();
    int row = blockIdx.x * 4 + (threadIdx.x >> 6);
    if (row >= ndst) return;
    int lane = threadIdx.x & 63;
    int beg = off[row], end = off[row + 1];
    float a0[4] = {0.f, 0.f, 0.f, 0.f};
    float a1[4] = {0.f, 0.f, 0.f, 0.f};
    int j = beg;
    for (; j + 8 <= end; j += 8) {
        int vv[8]; unsigned gg[8];
        #pragma unroll
        for (int u = 0; u < 8; ++u) vv[u] = epack[j + u];
        #pragma unroll
        for (int u = 0; u < 8; ++u)
            gg[u] = *(const unsigned*)(h + (size_t)(vv[u] & 0x0FFFFFFF) * DD + 2 * lane);
        #pragma unroll
        for (int u = 0; u < 8; ++u) {
            float4 c = cmp4[vv[u] >> 28];
            float x0 = b2f((u16)(gg[u] & 0xffffu));
            float x1 = b2f((u16)(gg[u] >> 16));
            a0[0] = fmaf(c.x, x0, a0[0]); a1[0] = fmaf(c.x, x1, a1[0]);
            a0[1] = fmaf(c.y, x0, a0[1]); a1[1] = fmaf(c.y, x1, a1[1]);
            a0[2] = fmaf(c.z, x0, a0[2]); a1[2] = fmaf(c.z, x1, a1[2]);
            a0[3] = fmaf(c.w, x0, a0[3]); a1[3] = fmaf(c.w, x1, a1[3]);
        }
    }
    for (; j < end; ++j) {
        int v = epack[j];
        unsigned g = *(const unsigned*)(h + (size_t)(v & 0x0FFFFFFF) * DD + 2 * lane);
        float4 c = cmp4[v >> 28];
        float x0 = b2f((u16)(g & 0xffffu));
        float x1 = b2f((u16)(g >> 16));
        a0[0] = fmaf(c.x, x0, a0[0]); a1[0] = fmaf(c.x, x1, a1[0]);
        a0[1] = fmaf(c.y, x0, a0[1]); a1[1] = fmaf(c.y, x1, a1[1]);
        a0[2] = fmaf(c.z, x0, a0[2]); a1[2] = fmaf(c.z, x1, a1[2]);
        a0[3] = fmaf(c.w, x0, a0[3]); a1[3] = fmaf(c.w, x1, a1[3]);
    }
    float inv = 1.f / fmaxf((float)(end - beg), 1.f);
    #pragma unroll
    for (int b = 0; b < 4; ++b) {
        unsigned pk = (unsigned)f2b(a0[b] * inv) | ((unsigned)f2b(a1[b] * inv) << 16);
        *(unsigned*)(T + ((size_t)b * ndst + row) * DD + 2 * lane) = pk;
    }
}

// ---- 32x32x16 MFMA GEMM, one 32-row m-tile per wave, A fully prefetched ----
// C[nrows x 128] = sum_p Ap[p]@Wp[p] + Ar@Wr + bias, optional LN/ReLU.
// W in fragment order (see wconv). A: [row][k].
// C/D layout: col=lane&31, row=(reg&3)+8*(reg>>2)+4*(lane>>5)  [m74/m101].
template<int WPB, bool OBF16, bool RELU, bool AF32, bool LN>
__global__ __launch_bounds__(WPB * 64) void mfma_gemm(
    const u16* __restrict__ Ap, int nplanes, const void* __restrict__ Ar,
    const u16* __restrict__ Wp, const u16* __restrict__ Wr,
    const float* __restrict__ bias, const float* __restrict__ gw,
    const float* __restrict__ bw, void* __restrict__ Cv, int nrows)
{
    int wave = threadIdx.x >> 6;
    int lane = threadIdx.x & 63;
    int l31 = lane & 31, half = lane >> 5;
    int m0 = (blockIdx.x * WPB + wave) * 32;
    int arow = m0 + l31;
    bool rv = arow < nrows;
    f32x16 acc[4];
    #pragma unroll
    for (int t = 0; t < 4; ++t)
        #pragma unroll
        for (int i = 0; i < 16; ++i) acc[t][i] = 0.f;

    if (AF32) {
        // single plane (root, f32 A): stage all 16 float4 loads up-front
        const float* Aq = (const float*)Ar + (size_t)arow * DD;
        float4 st[16];
        if (rv) {
            #pragma unroll
            for (int c = 0; c < 16; ++c)
                st[c] = *(const float4*)(Aq + ((c >> 1) * 16 + half * 8) + (c & 1) * 4);
        } else {
            #pragma unroll
            for (int c = 0; c < 16; ++c) st[c] = make_float4(0.f, 0.f, 0.f, 0.f);
        }
        #pragma unroll
        for (int kc = 0; kc < 8; ++kc) {
            bf16x8 bfr[4];
            #pragma unroll
            for (int t = 0; t < 4; ++t)
                bfr[t] = *(const bf16x8*)(Wr + (size_t)((kc * 4 + t) * 64 + lane) * 8);
            float4 u0 = st[2 * kc], u1 = st[2 * kc + 1];
            bf16x8 af;
            af[0] = (short)f2b(u0.x); af[1] = (short)f2b(u0.y);
            af[2] = (short)f2b(u0.z); af[3] = (short)f2b(u0.w);
            af[4] = (short)f2b(u1.x); af[5] = (short)f2b(u1.y);
            af[6] = (short)f2b(u1.z); af[7] = (short)f2b(u1.w);
            #pragma unroll
            for (int t = 0; t < 4; ++t)
                acc[t] = __builtin_amdgcn_mfma_f32_32x32x16_bf16(af, bfr[t], acc[t], 0, 0, 0);
        }
    } else {
        bf16x8 A0[8], A1[8];
        {
            const u16* Ainit = (nplanes == 0) ? (const u16*)Ar : Ap;
            if (rv) {
                #pragma unroll
                for (int c = 0; c < 8; ++c)
                    A0[c] = *(const bf16x8*)(Ainit + (size_t)arow * DD + c * 16 + half * 8);
            } else {
                #pragma unroll
                for (int c = 0; c < 8; ++c) A0[c] = (bf16x8){0,0,0,0,0,0,0,0};
            }
        }
        for (int p = 0; p <= nplanes; ++p) {
            const u16* Wsel = (p == nplanes) ? Wr : Wp + p * 16384;
            if (p < nplanes) {
                const u16* An = (p + 1 == nplanes) ? (const u16*)Ar
                                                   : Ap + (size_t)(p + 1) * nrows * DD;
                if (rv) {
                    #pragma unroll
                    for (int c = 0; c < 8; ++c)
                        A1[c] = *(const bf16x8*)(An + (size_t)arow * DD + c * 16 + half * 8);
                } else {
                    #pragma unroll
                    for (int c = 0; c < 8; ++c) A1[c] = (bf16x8){0,0,0,0,0,0,0,0};
                }
            }
            #pragma unroll
            for (int kc = 0; kc < 8; ++kc) {
                bf16x8 bfr[4];
                #pragma unroll
                for (int t = 0; t < 4; ++t)
                    bfr[t] = *(const bf16x8*)(Wsel + (size_t)((kc * 4 + t) * 64 + lane) * 8);
                #pragma unroll
                for (int t = 0; t < 4; ++t)
                    acc[t] = __builtin_amdgcn_mfma_f32_32x32x16_bf16(A0[kc], bfr[t], acc[t], 0, 0, 0);
            }
            if (p < nplanes) {
                #pragma unroll
                for (int c = 0; c < 8; ++c) A0[c] = A1[c];
            }
        }
    }

    float bb[4];
    #pragma unroll
    for (int t = 0; t < 4; ++t) bb[t] = bias[t * 32 + l31];
    float gg[4], ww[4];
    if (LN) {
        #pragma unroll
        for (int t = 0; t < 4; ++t) { gg[t] = gw[t * 32 + l31]; ww[t] = bw[t * 32 + l31]; }
    }

    #pragma unroll
    for (int reg = 0; reg < 16; ++reg) {
        int rl = (reg & 3) + 8 * (reg >> 2) + 4 * half;
        int row = m0 + rl;
        float v[4];
        #pragma unroll
        for (int t = 0; t < 4; ++t) v[t] = acc[t][reg] + bb[t];
        if (LN) {
            float s1 = 0.f, s2 = 0.f;
            #pragma unroll
            for (int t = 0; t < 4; ++t) { s1 += v[t]; s2 += v[t] * v[t]; }
            #pragma unroll
            for (int o = 1; o < 32; o <<= 1) {
                s1 += __shfl_xor(s1, o);
                s2 += __shfl_xor(s2, o);
            }
            float mu = s1 * (1.f / 128.f);
            float var = s2 * (1.f / 128.f) - mu * mu;
            float rstd = rsqrtf(fmaxf(var, 0.f) + 1e-5f);
            #pragma unroll
            for (int t = 0; t < 4; ++t) v[t] = (v[t] - mu) * rstd * gg[t] + ww[t];
        }
        if (RELU || LN) {
            #pragma unroll
            for (int t = 0; t < 4; ++t) v[t] = fmaxf(v[t], 0.f);
        }
        if (row < nrows) {
            #pragma unroll
            for (int t = 0; t < 4; ++t) {
                if (OBF16) ((u16*)Cv)[(size_t)row * DD + t * 32 + l31] = f2b(v[t]);
                else       ((float*)Cv)[(size_t)row * DD + t * 32 + l31] = v[t];
            }
        }
    }
}

extern "C" void kernel_launch(void* const* d_in, const int* in_sizes, int n_in,
                              void* d_out, int out_size, void* d_ws, size_t ws_size,
                              hipStream_t stream)
{
    const float* x     = (const float*)d_in[0];
    const int* src0    = (const int*)d_in[1];
    const int* dst0    = (const int*)d_in[2];
    const int* eid0    = (const int*)d_in[3];
    const int* src1    = (const int*)d_in[4];
    const int* dst1    = (const int*)d_in[5];
    const int* eid1    = (const int*)d_in[6];
    const int* etype   = (const int*)d_in[7];
    const float* preW  = (const float*)d_in[8];
    const float* preb  = (const float*)d_in[9];
    const float* basis0 = (const float*)d_in[10];
    const float* comp0  = (const float*)d_in[11];
    const float* root0  = (const float*)d_in[12];
    const float* bias0  = (const float*)d_in[13];
    const float* g0    = (const float*)d_in[14];
    const float* be0   = (const float*)d_in[15];
    const float* basis1 = (const float*)d_in[16];
    const float* comp1  = (const float*)d_in[17];
    const float* root1  = (const float*)d_in[18];
    const float* bias1  = (const float*)d_in[19];
    const float* g1    = (const float*)d_in[20];
    const float* be1   = (const float*)d_in[21];
    const float* postW = (const float*)d_in[22];
    const float* postb = (const float*)d_in[23];
    float* out = (float*)d_out;

    const int N0 = 120000, N1 = N1C, N2 = N2C;
    const int E0 = E0C, E1 = E1C;

    char* ws = (char*)d_ws;
    size_t o = 0;
    auto alloc = [&](size_t bytes) { char* p = ws + o; o += (bytes + 255) & ~(size_t)255; return p; };
    u16* h0    = (u16*)alloc((size_t)N0 * DD * 2);
    u16* T0    = (u16*)alloc((size_t)4 * N1 * DD * 2);
    u16* h1    = (u16*)alloc((size_t)N1 * DD * 2);
    u16* T1    = (u16*)alloc((size_t)4 * N2 * DD * 2);
    u16* h2    = (u16*)alloc((size_t)N2 * DD * 2);
    u16* wt    = (u16*)alloc((size_t)12 * 16384 * 2);
    int* off0  = (int*)alloc((size_t)(N1 + 1) * 4);
    int* off1  = (int*)alloc((size_t)(N2 + 1) * 4);
    int* cntz  = (int*)alloc((size_t)(2 * N1 + 2 * N2) * 4);
    int* cnt0 = cntz, *cur0 = cntz + N1, *cnt1 = cntz + 2 * N1, *cur1 = cntz + 2 * N1 + N2;
    int* ep0   = (int*)alloc((size_t)E0 * 4);
    int* ep1   = (int*)alloc((size_t)E1 * 4);
    int* partials = (int*)alloc(64 * 4);

    hipMemsetAsync(cntz, 0, (size_t)(2 * N1 + 2 * N2) * 4, stream);

    // wt layout: [0]=pre, [1..4]=basis0, [5]=root0, [6..9]=basis1, [10]=root1, [11]=post
    WtJob job;
    job.src[0] = preW;
    for (int b = 0; b < 4; ++b) job.src[1 + b] = basis0 + (size_t)b * 16384;
    job.src[5] = root0;
    for (int b = 0; b < 4; ++b) job.src[6 + b] = basis1 + (size_t)b * 16384;
    job.src[10] = root1;
    job.src[11] = postW;
    wconv_kernel<<<192, 256, 0, stream>>>(job, wt);

    // CSR build
    hist_all<<<(E0 + E1 + 255) / 256, 256, 0, stream>>>(dst0, dst1, cnt0, cnt1);
    scan_blocks<<<NB0 + NB1, 1024, 0, stream>>>(cnt0, cnt1, off0, off1, partials);
    scan_carry<<<1, 64, 0, stream>>>(partials, off0, off1);
    scan_add<<<NB0 + NB1, 1024, 0, stream>>>(partials, off0, off1);
    fill_all<<<(E0 + E1 + 255) / 256, 256, 0, stream>>>(
        src0, dst0, eid0, src1, dst1, eid1, etype, off0, off1, cur0, cur1, ep0, ep1);

    // h0 = relu(x @ preW + preb)
    mfma_gemm<4, true, true, true, false><<<(N0 + 127) / 128, 256, 0, stream>>>(
        nullptr, 0, x, nullptr, wt + 0 * 16384, preb, nullptr, nullptr, h0, N0);

    // layer 0: gather-agg + conv GEMM with fused LN+ReLU
    agg_kernel<<<(N1 + 3) / 4, 256, 0, stream>>>(h0, off0, ep0, comp0, T0, N1);
    mfma_gemm<4, true, false, false, true><<<(N1 + 127) / 128, 256, 0, stream>>>(
        T0, 4, h0, wt + 1 * 16384, wt + 5 * 16384, bias0, g0, be0, h1, N1);

    // layer 1
    agg_kernel<<<(N2 + 3) / 4, 256, 0, stream>>>(h1, off1, ep1, comp1, T1, N2);
    mfma_gemm<4, true, false, false, true><<<(N2 + 127) / 128, 256, 0, stream>>>(
        T1, 4, h1, wt + 6 * 16384, wt + 10 * 16384, bias1, g1, be1, h2, N2);

    // out = h2 @ postW + postb
    mfma_gemm<4, false, false, false, false><<<(N2 + 127) / 128, 256, 0, stream>>>(
        nullptr, 0, h2, nullptr, wt + 11 * 16384, postb, nullptr, nullptr, out, N2);
}